// Round 13
// baseline (123.550 us; speedup 1.0000x reference)
//
#include <hip/hip_runtime.h>
#include <hip/hip_bf16.h>

typedef _Float16 f16;
typedef _Float16 f16x8 __attribute__((ext_vector_type(8)));
typedef _Float16 f16x4 __attribute__((ext_vector_type(4)));
typedef float f32x4 __attribute__((ext_vector_type(4)));
typedef int i32x4 __attribute__((ext_vector_type(4)));

#define B_ 8
#define P_ 2048
#define Q_ 512
#define H_ 1024

__device__ __forceinline__ void gload_lds16(const void* g, void* l) {
  __builtin_amdgcn_global_load_lds(
      (const __attribute__((address_space(1))) void*)g,
      (__attribute__((address_space(3))) void*)l, 16, 0, 0);
}

// ---- f32 -> f16 convert (map_W) ----
__global__ __launch_bounds__(256) void k_cvt16(const float* __restrict__ x,
                                               f16* __restrict__ y, int n4) {
  int i = blockIdx.x * blockDim.x + threadIdx.x;
  int stride = gridDim.x * blockDim.x;
  for (; i < n4; i += stride) {
    f32x4 v = ((const f32x4*)x)[i];
    f16x4 h;
#pragma unroll
    for (int j = 0; j < 4; ++j) h[j] = (f16)v[j];
    ((f16x4*)y)[i] = h;
  }
}

// ---- question [B,Q,H] f32 -> qT [B,H,Q] f16 AND q16 [B,Q,H] f16 ----
__global__ __launch_bounds__(256) void k_transpose(const float* __restrict__ q,
                                                   f16* __restrict__ qT,
                                                   f16* __restrict__ q16) {
  __shared__ float t[64][65];
  int b = blockIdx.z;
  int h0 = blockIdx.x * 64, q0 = blockIdx.y * 64;
  int tid = threadIdx.x;
  int c4 = (tid & 15) * 4;
  int r16 = tid >> 4;
  const float* src = q + ((long)b * Q_ + q0) * H_ + h0;
  f16* d16 = q16 + ((long)b * Q_ + q0) * H_ + h0;
#pragma unroll
  for (int i = 0; i < 4; ++i) {
    int r = r16 + i * 16;
    f32x4 v = *(const f32x4*)(src + (long)r * H_ + c4);
    f16x4 s;
#pragma unroll
    for (int j = 0; j < 4; ++j) s[j] = (f16)v[j];
    *(f16x4*)(d16 + (long)r * H_ + c4) = s;
    t[c4 + 0][r] = v[0];
    t[c4 + 1][r] = v[1];
    t[c4 + 2][r] = v[2];
    t[c4 + 3][r] = v[3];
  }
  __syncthreads();
  f16* dst = qT + ((long)b * H_ + h0) * Q_ + q0;
#pragma unroll
  for (int i = 0; i < 4; ++i) {
    int hr = r16 + i * 16;
    f16x4 o;
#pragma unroll
    for (int j = 0; j < 4; ++j) o[j] = (f16)t[hr][c4 + j];
    *(f16x4*)(dst + (long)hr * Q_ + c4) = o;
  }
}

// ==== GEMM1 + partial masked softmax: 128x256 tile (R12 skeleton) ====
// Main loop identical to the R8/R12 116.7us build. Epilogue replaced:
// instead of writing S f32 (64MB), compute per-row over this block's 256
// cols: local masked max m_b, e=exp(t-m_b), write e*mk as f16 (16MB, L3-hot)
// + per-row partials (m_b, Z_b=sum e, Sm_b=sum e*mk) for exact cross-block
// combine in k_rowscale. Algebra identical to R1-proven softmax.
__global__ __launch_bounds__(512, 2) void k_gemm1(
    const float* __restrict__ passage, const f16* __restrict__ q16,
    const int* __restrict__ qmask, f16* __restrict__ alphaE,
    float* __restrict__ part) {
  constexpr int NT = H_ / 32;  // 32 K-tiles
  __shared__ __align__(16) f16 smem[40960];  // 80 KB

  int orig = blockIdx.x;  // 256 blocks: gx=2 (col), gy=16 (row), z=8
  int wg = (orig & 7) * 32 + (orig >> 3);  // T1 bijective; z == XCD
  int bx = wg & 1, by = (wg >> 1) & 15, z = wg >> 5;
  int row0 = by * 128, col0 = bx * 256;

  int tid = threadIdx.x, wv = tid >> 6, lane = tid & 63;
  int fr = lane & 15, kq = lane >> 4;
  int wr = (wv >> 2) * 64, wc = (wv & 3) * 64;
  int swz = (kq ^ ((fr >> 1) & 3)) * 8;

  int ar = tid >> 2, ac = tid & 3;
  const float* gA = passage + ((long)(z * P_ + row0 + ar)) * H_ + ac * 8;
  int aw = ar * 32 + ((ac ^ ((ar >> 1) & 3)) * 8);  // chunk-XOR swizzled

  const f16* gB = q16 + ((long)(z * Q_ + col0 + (tid >> 2))) * H_ +
                  (((tid & 3) ^ ((tid >> 3) & 3)) * 8);

  auto stageB = [&](int t) {
    const f16* g = gB + t * 32;
    f16* l = smem + 8192 + (t & 3) * 8192 + wv * 512;
    gload_lds16(g, l);
    gload_lds16(g + (long)128 * H_, l + 4096);
  };
  auto writeA = [&](int t, f32x4 lo, f32x4 hi) {
    f16x8 h;
#pragma unroll
    for (int j = 0; j < 4; ++j) {
      h[j] = (f16)lo[j];
      h[4 + j] = (f16)hi[j];
    }
    *(f16x8*)(smem + (t & 1) * 4096 + aw) = h;
  };

  f32x4 acc[4][4] = {};
  f32x4 a0lo, a0hi, a1lo, a1hi;  // named regs, static parity (rule 20)

  a0lo = *(const f32x4*)(gA);
  a0hi = *(const f32x4*)(gA + 4);
  a1lo = *(const f32x4*)(gA + 32);
  a1hi = *(const f32x4*)(gA + 36);
  stageB(0);
  stageB(1);
  stageB(2);
  writeA(0, a0lo, a0hi);
  asm volatile("s_waitcnt vmcnt(4) lgkmcnt(0)" ::: "memory");
  __builtin_amdgcn_s_barrier();
  __builtin_amdgcn_sched_barrier(0);

#pragma unroll 4
  for (int t = 0; t < NT; ++t) {
    if (t + 2 < NT) {
      const float* g = gA + (t + 2) * 32;
      if (t & 1) {
        a1lo = *(const f32x4*)(g);
        a1hi = *(const f32x4*)(g + 4);
      } else {
        a0lo = *(const f32x4*)(g);
        a0hi = *(const f32x4*)(g + 4);
      }
    }
    if (t + 3 < NT) stageB(t + 3);
    f16x8 af[4], bf[4];
    const f16* Ab = smem + (t & 1) * 4096;
    const f16* Bb = smem + 8192 + (t & 3) * 8192;
#pragma unroll
    for (int m = 0; m < 4; ++m)
      af[m] = *(const f16x8*)(Ab + (wr + m * 16 + fr) * 32 + swz);
#pragma unroll
    for (int n = 0; n < 4; ++n)
      bf[n] = *(const f16x8*)(Bb + (wc + n * 16 + fr) * 32 + swz);
    if (t + 1 < NT)
      writeA(t + 1, (t & 1) ? a0lo : a1lo, (t & 1) ? a0hi : a1hi);
    __builtin_amdgcn_s_setprio(1);
#pragma unroll
    for (int m = 0; m < 4; ++m)
#pragma unroll
      for (int n = 0; n < 4; ++n)
        acc[m][n] = __builtin_amdgcn_mfma_f32_16x16x32_f16(af[m], bf[n],
                                                           acc[m][n], 0, 0, 0);
    __builtin_amdgcn_s_setprio(0);
    if (t <= NT - 4)
      asm volatile("s_waitcnt vmcnt(6) lgkmcnt(0)" ::: "memory");
    else if (t == NT - 3)
      asm volatile("s_waitcnt vmcnt(4) lgkmcnt(0)" ::: "memory");
    else
      asm volatile("s_waitcnt vmcnt(0) lgkmcnt(0)" ::: "memory");
    if (t < NT - 1) {
      __builtin_amdgcn_s_barrier();
      __builtin_amdgcn_sched_barrier(0);
    }
  }

  // ==== partial masked-softmax epilogue ====
  // lane: row rloc = wr + m*16 + (lane>>4)*4 + j, col cloc = wc + n*16 + fr.
  __syncthreads();                   // all waves done with smem
  float* red = (float*)smem;         // [128][4] rowmax partials (6KB total)
  float* red2 = red + 512;           // [128][4][2] Z/Sm partials
  const int* qm = qmask + z * Q_ + col0;
  float mk[4];
#pragma unroll
  for (int n = 0; n < 4; ++n) mk[n] = (float)qm[wc + n * 16 + fr];

  int rbase = wr + (lane >> 4) * 4;  // + m*16 + j
  float mxl[4][4];
#pragma unroll
  for (int m = 0; m < 4; ++m)
#pragma unroll
    for (int j = 0; j < 4; ++j) {
      float v = acc[m][0][j] * mk[0];
#pragma unroll
      for (int n = 1; n < 4; ++n) v = fmaxf(v, acc[m][n][j] * mk[n]);
      v = fmaxf(v, __shfl_xor(v, 1, 64));
      v = fmaxf(v, __shfl_xor(v, 2, 64));
      v = fmaxf(v, __shfl_xor(v, 4, 64));
      v = fmaxf(v, __shfl_xor(v, 8, 64));
      if (fr == 0) red[(rbase + m * 16 + j) * 4 + (wv & 3)] = v;
    }
  __syncthreads();
#pragma unroll
  for (int m = 0; m < 4; ++m)
#pragma unroll
    for (int j = 0; j < 4; ++j) {
      int r = rbase + m * 16 + j;
      mxl[m][j] = fmaxf(fmaxf(red[r * 4], red[r * 4 + 1]),
                        fmaxf(red[r * 4 + 2], red[r * 4 + 3]));
    }
#pragma unroll
  for (int m = 0; m < 4; ++m)
#pragma unroll
    for (int j = 0; j < 4; ++j) {
      float zs = 0.f, ss = 0.f;
#pragma unroll
      for (int n = 0; n < 4; ++n) {
        float e = expf(acc[m][n][j] * mk[n] - mxl[m][j]);
        acc[m][n][j] = e * mk[n];  // store e*mk (what alpha is built from)
        zs += e;
        ss += e * mk[n];
      }
      zs += __shfl_xor(zs, 1, 64); ss += __shfl_xor(ss, 1, 64);
      zs += __shfl_xor(zs, 2, 64); ss += __shfl_xor(ss, 2, 64);
      zs += __shfl_xor(zs, 4, 64); ss += __shfl_xor(ss, 4, 64);
      zs += __shfl_xor(zs, 8, 64); ss += __shfl_xor(ss, 8, 64);
      if (fr == 0) {
        red2[((rbase + m * 16 + j) * 4 + (wv & 3)) * 2] = zs;
        red2[((rbase + m * 16 + j) * 4 + (wv & 3)) * 2 + 1] = ss;
      }
    }
  __syncthreads();
  f16* ap = alphaE + ((long)(z * P_ + row0)) * Q_ + col0;
#pragma unroll
  for (int m = 0; m < 4; ++m)
#pragma unroll
    for (int j = 0; j < 4; ++j) {
      int r = rbase + m * 16 + j;
      if ((wv & 3) == 0 && fr == 0) {
        float Z = 0.f, Sm = 0.f;
#pragma unroll
        for (int w = 0; w < 4; ++w) {
          Z += red2[(r * 4 + w) * 2];
          Sm += red2[(r * 4 + w) * 2 + 1];
        }
        float* pp = part + ((long)(z * 2 + bx) * P_ + row0 + r) * 4;
        pp[0] = mxl[m][j];
        pp[1] = Z;
        pp[2] = Sm;
      }
#pragma unroll
      for (int n = 0; n < 4; ++n)
        ap[(long)r * Q_ + wc + n * 16 + fr] = (f16)acc[m][n][j];
    }
}

// ---- combine the 2 column-block partials, rescale alpha in place ----
// alpha_q = e_q*mk_q * s_b * inv;  s_b = e^{m_b - M},
// inv = 1/(Sm0*s0 + Sm1*s1 + 1e-13*(Z0*s0 + Z1*s1)).  Exact vs reference.
__global__ __launch_bounds__(256) void k_rowscale(f16* __restrict__ alpha,
                                                  const float* __restrict__ part) {
  int row = blockIdx.x * 4 + (threadIdx.x >> 6);  // global row in [0, B*P)
  int lane = threadIdx.x & 63;
  int z = row >> 11, pr = row & 2047;
  const float* p0 = part + ((long)(z * 2 + 0) * P_ + pr) * 4;
  const float* p1 = part + ((long)(z * 2 + 1) * P_ + pr) * 4;
  float m0 = p0[0], Z0 = p0[1], S0 = p0[2];
  float m1 = p1[0], Z1 = p1[1], S1 = p1[2];
  float M = fmaxf(m0, m1);
  float s0 = expf(m0 - M), s1 = expf(m1 - M);
  float inv = 1.0f / (S0 * s0 + S1 * s1 + 1e-13f * (Z0 * s0 + Z1 * s1));
  float sc = (lane < 32 ? s0 : s1) * inv;  // lane*8 cols all in one half
  f16* ap = alpha + (long)row * Q_ + lane * 8;
  f16x8 v = *(f16x8*)ap;
#pragma unroll
  for (int j = 0; j < 8; ++j) v[j] = (f16)((float)v[j] * sc);
  *(f16x8*)ap = v;
}

// ---- 256x256-tile deep-pipelined GEMM (R7/R8/R12-proven single-phase) ----
template <int EPI, int NT>
__global__ __launch_bounds__(512, 2) void k_gemm256(
    const f16* __restrict__ A, const f16* __restrict__ Bm,
    void* __restrict__ Cv, const float* __restrict__ bias, int N, int gx,
    int gy, long sA, long sB, long sC) {
  constexpr int K = NT * 32;
  __shared__ __align__(16) f16 smem[65536];

  int nwg = gridDim.x;  // 256
  int orig = blockIdx.x;
  int wg = (orig & 7) * (nwg >> 3) + (orig >> 3);  // T1 bijective
  int bx = wg % gx;
  int tt = wg / gx;
  int by = tt % gy;
  int z = tt / gy;
  int row0 = by * 256, col0 = bx * 256;
  A += z * sA;
  Bm += z * sB;

  int tid = threadIdx.x, wv = tid >> 6, lane = tid & 63;

  bool isA = wv < 4;
  int u0 = (wv & 3) * 4;
  int srow = u0 * 16 + (lane >> 2);
  int sclog = ((lane & 3) ^ ((lane >> 3) & 3)) * 8;
  const f16* sbaseG = isA ? A + (long)(row0 + srow) * K + sclog
                          : Bm + (long)(col0 + srow) * K + sclog;
  int sbaseL = (isA ? 0 : 8192) + u0 * 512;

  auto stage = [&](int tile) {
    const f16* g = sbaseG + (long)tile * 32;
    f16* l = smem + (tile & 3) * 16384 + sbaseL;
#pragma unroll
    for (int j = 0; j < 4; ++j) gload_lds16(g + (long)j * 16 * K, l + j * 512);
  };

  int wr = (wv >> 2) * 128, wc = (wv & 3) * 64;
  int fr = lane & 15, kq = lane >> 4;
  int swz = (kq ^ ((fr >> 1) & 3)) * 8 + fr * 32;

  f32x4 acc[8][4] = {};
  auto compute = [&](int t) {
    const f16* bufA = smem + (t & 3) * 16384;
    const f16* bufB = bufA + 8192;
    f16x8 af[8], bfr[4];
#pragma unroll
    for (int m = 0; m < 8; ++m)
      af[m] = *(const f16x8*)(bufA + (wr + m * 16) * 32 + swz);
#pragma unroll
    for (int n = 0; n < 4; ++n)
      bfr[n] = *(const f16x8*)(bufB + (wc + n * 16) * 32 + swz);
#pragma unroll
    for (int m = 0; m < 8; ++m)
#pragma unroll
      for (int n = 0; n < 4; ++n)
        acc[m][n] = __builtin_amdgcn_mfma_f32_16x16x32_f16(af[m], bfr[n],
                                                           acc[m][n], 0, 0, 0);
  };

  stage(0);
  stage(1);
  stage(2);
  asm volatile("s_waitcnt vmcnt(8)" ::: "memory");
  __builtin_amdgcn_s_barrier();
  __builtin_amdgcn_sched_barrier(0);
  for (int t = 0; t < NT - 3; ++t) {
    stage(t + 3);
    compute(t);
    asm volatile("s_waitcnt vmcnt(8)" ::: "memory");
    __builtin_amdgcn_s_barrier();
    __builtin_amdgcn_sched_barrier(0);
  }
  compute(NT - 3);
  asm volatile("s_waitcnt vmcnt(4)" ::: "memory");
  __builtin_amdgcn_s_barrier();
  __builtin_amdgcn_sched_barrier(0);
  compute(NT - 2);
  asm volatile("s_waitcnt vmcnt(0)" ::: "memory");
  __builtin_amdgcn_s_barrier();
  __builtin_amdgcn_sched_barrier(0);
  compute(NT - 1);

  int r0 = row0 + wr + (lane >> 4) * 4;
  int c0 = col0 + wc + fr;
  if constexpr (EPI == 1) {
    f16* C = (f16*)Cv + z * sC;
#pragma unroll
    for (int m = 0; m < 8; ++m)
#pragma unroll
      for (int n = 0; n < 4; ++n)
#pragma unroll
        for (int j = 0; j < 4; ++j)
          C[(long)(r0 + m * 16 + j) * N + c0 + n * 16] = (f16)acc[m][n][j];
  } else {
    float* C = (float*)Cv;
#pragma unroll
    for (int n = 0; n < 4; ++n) {
      float bv = bias[c0 + n * 16];
#pragma unroll
      for (int m = 0; m < 8; ++m)
#pragma unroll
        for (int j = 0; j < 4; ++j) {
          float v = acc[m][n][j] + bv;
          // write-only output: nontemporal (R11: WRITE_SIZE 86->70 MB)
          __builtin_nontemporal_store(
              fmaxf(v, 0.f), &C[(long)(r0 + m * 16 + j) * N + c0 + n * 16]);
        }
    }
  }
}

extern "C" void kernel_launch(void* const* d_in, const int* in_sizes, int n_in,
                              void* d_out, int out_size, void* d_ws,
                              size_t ws_size, hipStream_t stream) {
  const float* passage = (const float*)d_in[0];
  const float* question = (const float*)d_in[1];
  const int* qmask = (const int*)d_in[2];
  const float* mapW = (const float*)d_in[3];
  const float* mapb = (const float*)d_in[4];

  char* ws = (char*)d_ws;
  size_t off = 0;
  auto alloc = [&](size_t bytes) {
    void* p = ws + off;
    off += (bytes + 255) & ~(size_t)255;
    return p;
  };
  f16* q16 = (f16*)alloc((size_t)B_ * Q_ * H_ * 2);
  f16* qT = (f16*)alloc((size_t)B_ * H_ * Q_ * 2);
  f16* w16 = (f16*)alloc((size_t)H_ * H_ * 2);
  f16* alpha = (f16*)alloc((size_t)B_ * P_ * Q_ * 2);
  f16* O = (f16*)alloc((size_t)B_ * P_ * H_ * 2);
  float* part = (float*)alloc((size_t)B_ * 2 * P_ * 4 * 4);

  k_cvt16<<<512, 256, 0, stream>>>(mapW, w16, H_ * H_ / 4);
  k_transpose<<<dim3(H_ / 64, Q_ / 64, B_), 256, 0, stream>>>(question, qT,
                                                              q16);

  // GEMM1 + partial softmax: e*mk (f16) + per-row per-colblock partials
  k_gemm1<<<256, 512, 0, stream>>>(passage, q16, qmask, alpha, part);

  // exact cross-block combine + in-place rescale -> alpha
  k_rowscale<<<B_ * P_ / 4, 256, 0, stream>>>(alpha, part);

  // GEMM3: O = alpha @ question  (4 x 8 x 8 = 256 tiles == 256 blocks)
  k_gemm256<1, Q_ / 32><<<256, 512, 0, stream>>>(
      alpha, qT, O, nullptr, H_, H_ / 256, P_ / 256, (long)P_ * Q_,
      (long)H_ * Q_, (long)P_ * H_);

  // GEMM4: Y = relu(O @ W^T + b)  (4 x 64 x 1 = 256 tiles == 256 blocks)
  k_gemm256<2, H_ / 32><<<256, 512, 0, stream>>>(
      O, w16, d_out, mapb, H_, H_ / 256, (B_ * P_) / 256, 0, 0, 0);
}